// Round 1
// baseline (1966.056 us; speedup 1.0000x reference)
//
#include <hip/hip_runtime.h>
#include <math.h>

#define B_ 512
#define L_ 100
#define D_ 1024
#define POS_DIM_ 50

// ---------- fast device math ----------
__device__ __forceinline__ float fast_tanh(float x) {
    // tanh(x) = 1 - 2/(exp(2x)+1); exact at saturation, ~1e-7 rel err mid-range
    float e = __expf(2.0f * x);
    return 1.0f - 2.0f * __builtin_amdgcn_rcpf(e + 1.0f);
}
__device__ __forceinline__ float fast_sigmoid(float x) {
    return __builtin_amdgcn_rcpf(1.0f + __expf(-x));
}

// ---------- Kernel 1: docs[b,d] = sum_{l<len} sent[b,l,d] / len ----------
__global__ __launch_bounds__(256) void docs_kernel(
    const float* __restrict__ sent, const int* __restrict__ doc_lens,
    float* __restrict__ docs)
{
    int b = blockIdx.x;
    int tid = threadIdx.x;
    int len = doc_lens[b];
    float inv = 1.0f / (float)len;
    const float* p = sent + (size_t)b * L_ * D_ + tid * 4;
    float4 acc = {0.f, 0.f, 0.f, 0.f};
    for (int l = 0; l < len; ++l) {
        float4 v = *(const float4*)(p + (size_t)l * D_);
        acc.x += v.x; acc.y += v.y; acc.z += v.z; acc.w += v.w;
    }
    acc.x *= inv; acc.y *= inv; acc.z *= inv; acc.w *= inv;
    *(float4*)(docs + (size_t)b * D_ + tid * 4) = acc;
}

// ---------- Kernel 2: tiny embedding dots ----------
__global__ void emb_kernel(const float* __restrict__ abs_emb,
                           const float* __restrict__ rel_emb,
                           const float* __restrict__ abs_w,
                           const float* __restrict__ rel_w,
                           float* __restrict__ abs_p, float* __restrict__ rel_vals)
{
    int t = threadIdx.x;
    if (t < L_) {
        float a = 0.f;
        for (int j = 0; j < POS_DIM_; ++j) a += abs_emb[t * POS_DIM_ + j] * abs_w[j];
        abs_p[t] = a;
    }
    if (t < 10) {
        float r = 0.f;
        for (int j = 0; j < POS_DIM_; ++j) r += rel_emb[t * POS_DIM_ + j] * rel_w[j];
        rel_vals[t] = r;
    }
}

// ---------- Kernel 3: fp32 tiled GEMM, C[M,N] = A[M,K] * W ----------
// WMODE 0: W is [K,N] row-major (use W[k*N+n])
// WMODE 1: W is [N,K] row-major (use W[n*K+k])
// EPI 0: C = acc
// EPI 1: C = tanh(acc + X[n])
// EPI 2: C = acc + X[n]
template<int WMODE, int EPI>
__global__ __launch_bounds__(256) void gemm64(
    const float* __restrict__ A, const float* __restrict__ W,
    const float* __restrict__ X, float* __restrict__ C,
    int M, int N, int K)
{
    __shared__ float As[16][68];
    __shared__ float Ws[16][68];
    int tid = threadIdx.x;
    int m0 = blockIdx.x * 64;
    int n0 = blockIdx.y * 64;
    int tx = tid & 15, ty = tid >> 4;
    float acc[4][4] = {};

    for (int k0 = 0; k0 < K; k0 += 16) {
        // A tile: 64 rows x 16 k, store transposed As[k][m]
        {
            int c = tid & 15;
            int r0 = tid >> 4;
            #pragma unroll
            for (int i = 0; i < 4; ++i) {
                int r = r0 + 16 * i;
                As[c][r] = A[(size_t)(m0 + r) * K + k0 + c];
            }
        }
        if (WMODE == 1) {
            int c = tid & 15;
            int r0 = tid >> 4;
            #pragma unroll
            for (int i = 0; i < 4; ++i) {
                int r = r0 + 16 * i;
                Ws[c][r] = W[(size_t)(n0 + r) * K + k0 + c];
            }
        } else {
            int n = tid & 63;
            int kk0 = tid >> 6;  // 0..3
            #pragma unroll
            for (int i = 0; i < 4; ++i) {
                int kk = kk0 + 4 * i;
                Ws[kk][n] = W[(size_t)(k0 + kk) * N + n0 + n];
            }
        }
        __syncthreads();
        #pragma unroll
        for (int kk = 0; kk < 16; ++kk) {
            float a[4], w[4];
            #pragma unroll
            for (int i = 0; i < 4; ++i) a[i] = As[kk][ty * 4 + i];
            #pragma unroll
            for (int j = 0; j < 4; ++j) w[j] = Ws[kk][tx * 4 + j];
            #pragma unroll
            for (int i = 0; i < 4; ++i)
                #pragma unroll
                for (int j = 0; j < 4; ++j)
                    acc[i][j] = fmaf(a[i], w[j], acc[i][j]);
        }
        __syncthreads();
    }

    #pragma unroll
    for (int i = 0; i < 4; ++i) {
        int m = m0 + ty * 4 + i;
        #pragma unroll
        for (int j = 0; j < 4; ++j) {
            int n = n0 + tx * 4 + j;
            float v = acc[i][j];
            if (EPI == 1) v = tanhf(v + X[n]);
            else if (EPI == 2) v = v + X[n];
            C[(size_t)m * N + n] = v;
        }
    }
}

// ---------- Kernel 4: sequential scan, one block per batch ----------
// pre_t = h_t . u_b + abs_p[t] + rel_vals[idx] + bias
// novelty_t = - hWn_t . tanh(s)
// prob = sigmoid(pre_t + novelty_t); s += prob * h_t
__global__ __launch_bounds__(256) void scan_kernel(
    const float* __restrict__ sent, const float* __restrict__ hWn,
    const float* __restrict__ u, const float* __restrict__ abs_p,
    const float* __restrict__ rel_vals, const float* __restrict__ bias,
    const int* __restrict__ doc_lens, float* __restrict__ out)
{
    int b = blockIdx.x;
    int tid = threadIdx.x;
    int wave = tid >> 6, lane = tid & 63;
    int len = doc_lens[b];
    float lenf = (float)len;

    // zero the masked tail
    for (int l = len + tid; l < L_; l += 256) out[b * L_ + l] = 0.f;

    float4 u4 = *(const float4*)(u + (size_t)b * D_ + tid * 4);
    const float* sb = sent + (size_t)b * L_ * D_ + tid * 4;
    const float* wb = hWn + (size_t)b * L_ * D_ + tid * 4;
    float biasv = bias[0];

    float s0 = 0.f, s1 = 0.f, s2 = 0.f, s3 = 0.f;
    __shared__ float red[2][2][4];

    for (int t = 0; t < len; ++t) {
        float4 h4 = *(const float4*)(sb + (size_t)t * D_);
        float4 w4 = *(const float4*)(wb + (size_t)t * D_);

        float r1 = w4.x * fast_tanh(s0) + w4.y * fast_tanh(s1)
                 + w4.z * fast_tanh(s2) + w4.w * fast_tanh(s3);
        float r2 = h4.x * u4.x + h4.y * u4.y + h4.z * u4.z + h4.w * u4.w;

        #pragma unroll
        for (int off = 32; off; off >>= 1) {
            r1 += __shfl_xor(r1, off);
            r2 += __shfl_xor(r2, off);
        }
        if (lane == 0) { red[t & 1][0][wave] = r1; red[t & 1][1][wave] = r2; }
        __syncthreads();
        r1 = red[t & 1][0][0] + red[t & 1][0][1] + red[t & 1][0][2] + red[t & 1][0][3];
        r2 = red[t & 1][1][0] + red[t & 1][1][1] + red[t & 1][1][2] + red[t & 1][1][3];

        int ridx = (int)rintf((float)(t + 1) * 9.0f / lenf);
        ridx = min(max(ridx, 0), 9);
        float pre = r2 + abs_p[t] + rel_vals[ridx] + biasv - r1;
        float prob = fast_sigmoid(pre);

        if (tid == 0) out[b * L_ + t] = prob;

        s0 = fmaf(prob, h4.x, s0);
        s1 = fmaf(prob, h4.y, s1);
        s2 = fmaf(prob, h4.z, s2);
        s3 = fmaf(prob, h4.w, s3);
    }
}

// ---------- launch ----------
extern "C" void kernel_launch(void* const* d_in, const int* in_sizes, int n_in,
                              void* d_out, int out_size, void* d_ws, size_t ws_size,
                              hipStream_t stream)
{
    const float* sent      = (const float*)d_in[0];
    const float* fc_w      = (const float*)d_in[1];
    const float* fc_b      = (const float*)d_in[2];
    const float* content_w = (const float*)d_in[3];
    const float* sal_w     = (const float*)d_in[4];
    const float* nov_w     = (const float*)d_in[5];
    const float* abs_emb   = (const float*)d_in[6];
    const float* rel_emb   = (const float*)d_in[7];
    const float* abs_w     = (const float*)d_in[8];
    const float* rel_w     = (const float*)d_in[9];
    const float* bias      = (const float*)d_in[10];
    const int*   doc_lens  = (const int*)d_in[11];
    float* out = (float*)d_out;

    char* ws = (char*)d_ws;
    float* docs     = (float*)ws;                       // 512*1024
    float* doc_vec  = docs + (size_t)B_ * D_;           // 512*1024
    float* u        = doc_vec + (size_t)B_ * D_;        // 512*1024
    float* abs_p    = u + (size_t)B_ * D_;              // 128
    float* rel_vals = abs_p + 128;                      // 16
    float* hWn      = (float*)(ws + (size_t)8 * 1024 * 1024);  // 51200*1024 f32 = 200 MiB

    // 1) docs (masked mean over valid sentences)
    docs_kernel<<<dim3(B_), 256, 0, stream>>>(sent, doc_lens, docs);

    // 2) tiny embedding dots
    emb_kernel<<<dim3(1), 128, 0, stream>>>(abs_emb, rel_emb, abs_w, rel_w, abs_p, rel_vals);

    // 3) doc_vec = tanh(docs @ fc_w^T + fc_b)   [W as [N,K], EPI tanh+bias]
    gemm64<1, 1><<<dim3(B_ / 64, D_ / 64), 256, 0, stream>>>(
        docs, fc_w, fc_b, doc_vec, B_, D_, D_);

    // 4) u = doc_vec @ sal_w^T + content_w      [W as [N,K], EPI add]
    gemm64<1, 2><<<dim3(B_ / 64, D_ / 64), 256, 0, stream>>>(
        doc_vec, sal_w, content_w, u, B_, D_, D_);

    // 5) hWn = sent_out @ nov_w                 [W as [K,N], plain]
    gemm64<0, 0><<<dim3((B_ * L_) / 64, D_ / 64), 256, 0, stream>>>(
        sent, nov_w, nullptr, hWn, B_ * L_, D_, D_);

    // 6) sequential scan over positions
    scan_kernel<<<dim3(B_), 256, 0, stream>>>(
        sent, hWn, u, abs_p, rel_vals, bias, doc_lens, out);
}

// Round 2
// 874.709 us; speedup vs baseline: 2.2477x; 2.2477x over previous
//
#include <hip/hip_runtime.h>
#include <math.h>

#define B_ 512
#define L_ 100
#define D_ 1024
#define POS_DIM_ 50

typedef _Float16 half8 __attribute__((ext_vector_type(8)));
typedef _Float16 half4 __attribute__((ext_vector_type(4)));
typedef float floatx4 __attribute__((ext_vector_type(4)));

// ---------- fast device math ----------
__device__ __forceinline__ float fast_tanh(float x) {
    float e = __expf(2.0f * x);
    return 1.0f - 2.0f * __builtin_amdgcn_rcpf(e + 1.0f);
}
__device__ __forceinline__ float fast_sigmoid(float x) {
    return __builtin_amdgcn_rcpf(1.0f + __expf(-x));
}

// ---------- Kernel 1: docs[b,d] = sum_{l<len} sent[b,l,d] / len ----------
__global__ __launch_bounds__(256) void docs_kernel(
    const float* __restrict__ sent, const int* __restrict__ doc_lens,
    float* __restrict__ docs)
{
    int b = blockIdx.x;
    int tid = threadIdx.x;
    int len = doc_lens[b];
    float inv = 1.0f / (float)len;
    const float* p = sent + (size_t)b * L_ * D_ + tid * 4;
    float4 acc = {0.f, 0.f, 0.f, 0.f};
    for (int l = 0; l < len; ++l) {
        float4 v = *(const float4*)(p + (size_t)l * D_);
        acc.x += v.x; acc.y += v.y; acc.z += v.z; acc.w += v.w;
    }
    acc.x *= inv; acc.y *= inv; acc.z *= inv; acc.w *= inv;
    *(float4*)(docs + (size_t)b * D_ + tid * 4) = acc;
}

// ---------- Kernel 2: tiny embedding dots ----------
__global__ void emb_kernel(const float* __restrict__ abs_emb,
                           const float* __restrict__ rel_emb,
                           const float* __restrict__ abs_w,
                           const float* __restrict__ rel_w,
                           float* __restrict__ abs_p, float* __restrict__ rel_vals)
{
    int t = threadIdx.x;
    if (t < L_) {
        float a = 0.f;
        for (int j = 0; j < POS_DIM_; ++j) a += abs_emb[t * POS_DIM_ + j] * abs_w[j];
        abs_p[t] = a;
    }
    if (t < 10) {
        float r = 0.f;
        for (int j = 0; j < POS_DIM_; ++j) r += rel_emb[t * POS_DIM_ + j] * rel_w[j];
        rel_vals[t] = r;
    }
}

// ---------- Kernel 3: fp32 tiled GEMM (small GEMMs only) ----------
// WMODE 1: W is [N,K] row-major. EPI 1: tanh(acc+X[n]); EPI 2: acc+X[n]
template<int WMODE, int EPI>
__global__ __launch_bounds__(256) void gemm64(
    const float* __restrict__ A, const float* __restrict__ W,
    const float* __restrict__ X, float* __restrict__ C,
    int M, int N, int K)
{
    __shared__ float As[16][68];
    __shared__ float Ws[16][68];
    int tid = threadIdx.x;
    int m0 = blockIdx.x * 64;
    int n0 = blockIdx.y * 64;
    int tx = tid & 15, ty = tid >> 4;
    float acc[4][4] = {};

    for (int k0 = 0; k0 < K; k0 += 16) {
        {
            int c = tid & 15;
            int r0 = tid >> 4;
            #pragma unroll
            for (int i = 0; i < 4; ++i) {
                int r = r0 + 16 * i;
                As[c][r] = A[(size_t)(m0 + r) * K + k0 + c];
            }
        }
        if (WMODE == 1) {
            int c = tid & 15;
            int r0 = tid >> 4;
            #pragma unroll
            for (int i = 0; i < 4; ++i) {
                int r = r0 + 16 * i;
                Ws[c][r] = W[(size_t)(n0 + r) * K + k0 + c];
            }
        } else {
            int n = tid & 63;
            int kk0 = tid >> 6;
            #pragma unroll
            for (int i = 0; i < 4; ++i) {
                int kk = kk0 + 4 * i;
                Ws[kk][n] = W[(size_t)(k0 + kk) * N + n0 + n];
            }
        }
        __syncthreads();
        #pragma unroll
        for (int kk = 0; kk < 16; ++kk) {
            float a[4], w[4];
            #pragma unroll
            for (int i = 0; i < 4; ++i) a[i] = As[kk][ty * 4 + i];
            #pragma unroll
            for (int j = 0; j < 4; ++j) w[j] = Ws[kk][tx * 4 + j];
            #pragma unroll
            for (int i = 0; i < 4; ++i)
                #pragma unroll
                for (int j = 0; j < 4; ++j)
                    acc[i][j] = fmaf(a[i], w[j], acc[i][j]);
        }
        __syncthreads();
    }

    #pragma unroll
    for (int i = 0; i < 4; ++i) {
        int m = m0 + ty * 4 + i;
        #pragma unroll
        for (int j = 0; j < 4; ++j) {
            int n = n0 + tx * 4 + j;
            float v = acc[i][j];
            if (EPI == 1) v = tanhf(v + X[n]);
            else if (EPI == 2) v = v + X[n];
            C[(size_t)m * N + n] = v;
        }
    }
}

// ---------- Kernel 3b: transpose + f16 hi/lo split of nov_w ----------
// B[k][n] fp32 -> Bt_hi[n][k], Bt_lo[n][k] f16
__global__ __launch_bounds__(256) void convert_b(
    const float* __restrict__ B, _Float16* __restrict__ Bt_hi,
    _Float16* __restrict__ Bt_lo)
{
    __shared__ float ld[32][33];
    int k0 = blockIdx.x * 32, n0 = blockIdx.y * 32;
    int r  = threadIdx.x >> 3;
    int c4 = (threadIdx.x & 7) * 4;
    float4 v = *(const float4*)(B + (size_t)(k0 + r) * D_ + n0 + c4);
    ld[r][c4] = v.x; ld[r][c4 + 1] = v.y; ld[r][c4 + 2] = v.z; ld[r][c4 + 3] = v.w;
    __syncthreads();
    half4 h, l;
    #pragma unroll
    for (int i = 0; i < 4; ++i) {
        float x = ld[c4 + i][r];
        _Float16 hi = (_Float16)x;
        float rem = x - (float)hi;
        h[i] = hi;
        l[i] = (_Float16)rem;
    }
    *(half4*)(Bt_hi + (size_t)(n0 + r) * D_ + k0 + c4) = h;
    *(half4*)(Bt_lo + (size_t)(n0 + r) * D_ + k0 + c4) = l;
}

// ---------- Kernel 4: MFMA f16-split GEMM: hWn = sent @ nov_w ----------
// A [M=51200, K=1024] fp32 (split on the fly), Bt_hi/lo [N=1024][K] f16.
// C = A_hi*B_hi + A_hi*B_lo + A_lo*B_hi  (fp32 accumulate) -> ~22-bit mantissa
#define GM 51200
#define GN 1024
#define GK 1024
#define LDT 40   // LDS row stride in f16 (80B: 8-row bank rotation covers 32 banks)

__global__ __launch_bounds__(256, 2) void gemm_hWn(
    const float* __restrict__ A, const _Float16* __restrict__ Bt_hi,
    const _Float16* __restrict__ Bt_lo, float* __restrict__ C)
{
    __shared__ _Float16 As_hi[128 * LDT];
    __shared__ _Float16 As_lo[128 * LDT];
    __shared__ _Float16 Bs_hi[128 * LDT];
    __shared__ _Float16 Bs_lo[128 * LDT];

    int tid  = threadIdx.x;
    int wave = tid >> 6, lane = tid & 63;
    int n0 = blockIdx.x * 128;   // fast dim: 8 n-blocks share A tile via L2
    int m0 = blockIdx.y * 128;
    int wm = (wave >> 1) * 64, wn = (wave & 1) * 64;
    int tm   = lane & 15;
    int quad = lane >> 4;

    floatx4 acc[4][4];
    #pragma unroll
    for (int i = 0; i < 4; ++i)
        #pragma unroll
        for (int j = 0; j < 4; ++j)
            acc[i][j] = (floatx4){0.f, 0.f, 0.f, 0.f};

    // staging: thread covers one (row, 16-element k-half)
    int sr = tid >> 1;
    int sh = tid & 1;
    const float*     Ap = A     + (size_t)(m0 + sr) * GK + sh * 16;
    const _Float16*  Bh = Bt_hi + (size_t)(n0 + sr) * GK + sh * 16;
    const _Float16*  Bl = Bt_lo + (size_t)(n0 + sr) * GK + sh * 16;
    int sbase = sr * LDT + sh * 16;

    #pragma unroll 1
    for (int k0 = 0; k0 < GK; k0 += 32) {
        float4 a0 = *(const float4*)(Ap + k0);
        float4 a1 = *(const float4*)(Ap + k0 + 4);
        float4 a2 = *(const float4*)(Ap + k0 + 8);
        float4 a3 = *(const float4*)(Ap + k0 + 12);
        half8 bh0 = *(const half8*)(Bh + k0);
        half8 bh1 = *(const half8*)(Bh + k0 + 8);
        half8 bl0 = *(const half8*)(Bl + k0);
        half8 bl1 = *(const half8*)(Bl + k0 + 8);

        half8 ah0, ah1, al0, al1;
        float af[16] = {a0.x, a0.y, a0.z, a0.w, a1.x, a1.y, a1.z, a1.w,
                        a2.x, a2.y, a2.z, a2.w, a3.x, a3.y, a3.z, a3.w};
        #pragma unroll
        for (int i = 0; i < 8; ++i) {
            _Float16 h = (_Float16)af[i];
            ah0[i] = h;
            al0[i] = (_Float16)(af[i] - (float)h);
        }
        #pragma unroll
        for (int i = 0; i < 8; ++i) {
            _Float16 h = (_Float16)af[8 + i];
            ah1[i] = h;
            al1[i] = (_Float16)(af[8 + i] - (float)h);
        }

        __syncthreads();   // previous iteration's LDS reads complete
        *(half8*)(As_hi + sbase)     = ah0;
        *(half8*)(As_hi + sbase + 8) = ah1;
        *(half8*)(As_lo + sbase)     = al0;
        *(half8*)(As_lo + sbase + 8) = al1;
        *(half8*)(Bs_hi + sbase)     = bh0;
        *(half8*)(Bs_hi + sbase + 8) = bh1;
        *(half8*)(Bs_lo + sbase)     = bl0;
        *(half8*)(Bs_lo + sbase + 8) = bl1;
        __syncthreads();

        half8 fa_hi[4], fa_lo[4], fb_hi[4], fb_lo[4];
        #pragma unroll
        for (int mt = 0; mt < 4; ++mt) {
            int row = (wm + mt * 16 + tm) * LDT + quad * 8;
            fa_hi[mt] = *(const half8*)(As_hi + row);
            fa_lo[mt] = *(const half8*)(As_lo + row);
        }
        #pragma unroll
        for (int nt = 0; nt < 4; ++nt) {
            int row = (wn + nt * 16 + tm) * LDT + quad * 8;
            fb_hi[nt] = *(const half8*)(Bs_hi + row);
            fb_lo[nt] = *(const half8*)(Bs_lo + row);
        }
        #pragma unroll
        for (int mt = 0; mt < 4; ++mt)
            #pragma unroll
            for (int nt = 0; nt < 4; ++nt) {
                acc[mt][nt] = __builtin_amdgcn_mfma_f32_16x16x32_f16(
                    fa_hi[mt], fb_hi[nt], acc[mt][nt], 0, 0, 0);
                acc[mt][nt] = __builtin_amdgcn_mfma_f32_16x16x32_f16(
                    fa_hi[mt], fb_lo[nt], acc[mt][nt], 0, 0, 0);
                acc[mt][nt] = __builtin_amdgcn_mfma_f32_16x16x32_f16(
                    fa_lo[mt], fb_hi[nt], acc[mt][nt], 0, 0, 0);
            }
    }

    // epilogue: C/D layout col = lane&15, row = quad*4 + reg
    #pragma unroll
    for (int mt = 0; mt < 4; ++mt) {
        #pragma unroll
        for (int nt = 0; nt < 4; ++nt) {
            int col = n0 + wn + nt * 16 + tm;
            int rowb = m0 + wm + mt * 16 + quad * 4;
            #pragma unroll
            for (int r = 0; r < 4; ++r)
                C[(size_t)(rowb + r) * GN + col] = acc[mt][nt][r];
        }
    }
}

// ---------- Kernel 5: sequential scan, one block per batch ----------
__global__ __launch_bounds__(256) void scan_kernel(
    const float* __restrict__ sent, const float* __restrict__ hWn,
    const float* __restrict__ u, const float* __restrict__ abs_p,
    const float* __restrict__ rel_vals, const float* __restrict__ bias,
    const int* __restrict__ doc_lens, float* __restrict__ out)
{
    int b = blockIdx.x;
    int tid = threadIdx.x;
    int wave = tid >> 6, lane = tid & 63;
    int len = doc_lens[b];
    float lenf = (float)len;

    for (int l = len + tid; l < L_; l += 256) out[b * L_ + l] = 0.f;

    float4 u4 = *(const float4*)(u + (size_t)b * D_ + tid * 4);
    const float* sb = sent + (size_t)b * L_ * D_ + tid * 4;
    const float* wb = hWn + (size_t)b * L_ * D_ + tid * 4;
    float biasv = bias[0];

    float s0 = 0.f, s1 = 0.f, s2 = 0.f, s3 = 0.f;
    __shared__ float red[2][2][4];

    for (int t = 0; t < len; ++t) {
        float4 h4 = *(const float4*)(sb + (size_t)t * D_);
        float4 w4 = *(const float4*)(wb + (size_t)t * D_);

        float r1 = w4.x * fast_tanh(s0) + w4.y * fast_tanh(s1)
                 + w4.z * fast_tanh(s2) + w4.w * fast_tanh(s3);
        float r2 = h4.x * u4.x + h4.y * u4.y + h4.z * u4.z + h4.w * u4.w;

        #pragma unroll
        for (int off = 32; off; off >>= 1) {
            r1 += __shfl_xor(r1, off);
            r2 += __shfl_xor(r2, off);
        }
        if (lane == 0) { red[t & 1][0][wave] = r1; red[t & 1][1][wave] = r2; }
        __syncthreads();
        r1 = red[t & 1][0][0] + red[t & 1][0][1] + red[t & 1][0][2] + red[t & 1][0][3];
        r2 = red[t & 1][1][0] + red[t & 1][1][1] + red[t & 1][1][2] + red[t & 1][1][3];

        int ridx = (int)rintf((float)(t + 1) * 9.0f / lenf);
        ridx = min(max(ridx, 0), 9);
        float pre = r2 + abs_p[t] + rel_vals[ridx] + biasv - r1;
        float prob = fast_sigmoid(pre);

        if (tid == 0) out[b * L_ + t] = prob;

        s0 = fmaf(prob, h4.x, s0);
        s1 = fmaf(prob, h4.y, s1);
        s2 = fmaf(prob, h4.z, s2);
        s3 = fmaf(prob, h4.w, s3);
    }
}

// ---------- launch ----------
extern "C" void kernel_launch(void* const* d_in, const int* in_sizes, int n_in,
                              void* d_out, int out_size, void* d_ws, size_t ws_size,
                              hipStream_t stream)
{
    const float* sent      = (const float*)d_in[0];
    const float* fc_w      = (const float*)d_in[1];
    const float* fc_b      = (const float*)d_in[2];
    const float* content_w = (const float*)d_in[3];
    const float* sal_w     = (const float*)d_in[4];
    const float* nov_w     = (const float*)d_in[5];
    const float* abs_emb   = (const float*)d_in[6];
    const float* rel_emb   = (const float*)d_in[7];
    const float* abs_w     = (const float*)d_in[8];
    const float* rel_w     = (const float*)d_in[9];
    const float* bias      = (const float*)d_in[10];
    const int*   doc_lens  = (const int*)d_in[11];
    float* out = (float*)d_out;

    char* ws = (char*)d_ws;
    const size_t MB = 1024 * 1024;
    float*     docs     = (float*)(ws);              // 2 MiB
    float*     doc_vec  = (float*)(ws + 2 * MB);     // 2 MiB
    float*     u        = (float*)(ws + 4 * MB);     // 2 MiB
    float*     abs_p    = (float*)(ws + 6 * MB);     // small
    float*     rel_vals = (float*)(ws + 6 * MB + 512);
    _Float16*  Bt_hi    = (_Float16*)(ws + 7 * MB);  // 2 MiB
    _Float16*  Bt_lo    = (_Float16*)(ws + 9 * MB);  // 2 MiB
    float*     hWn      = (float*)(ws + 12 * MB);    // 200 MiB

    // 1) docs (masked mean)
    docs_kernel<<<dim3(B_), 256, 0, stream>>>(sent, doc_lens, docs);

    // 2) embedding dots
    emb_kernel<<<dim3(1), 128, 0, stream>>>(abs_emb, rel_emb, abs_w, rel_w, abs_p, rel_vals);

    // 3) transpose + split nov_w
    convert_b<<<dim3(32, 32), 256, 0, stream>>>(nov_w, Bt_hi, Bt_lo);

    // 4) doc_vec = tanh(docs @ fc_w^T + fc_b)
    gemm64<1, 1><<<dim3(B_ / 64, D_ / 64), 256, 0, stream>>>(
        docs, fc_w, fc_b, doc_vec, B_, D_, D_);

    // 5) u = doc_vec @ sal_w^T + content_w
    gemm64<1, 2><<<dim3(B_ / 64, D_ / 64), 256, 0, stream>>>(
        doc_vec, sal_w, content_w, u, B_, D_, D_);

    // 6) hWn = sent @ nov_w via f16-split MFMA
    gemm_hWn<<<dim3(GN / 128, GM / 128), 256, 0, stream>>>(sent, Bt_hi, Bt_lo, hWn);

    // 7) sequential scan
    scan_kernel<<<dim3(B_), 256, 0, stream>>>(
        sent, hWn, u, abs_p, rel_vals, bias, doc_lens, out);
}

// Round 3
// 796.366 us; speedup vs baseline: 2.4688x; 1.0984x over previous
//
#include <hip/hip_runtime.h>
#include <math.h>

#define B_ 512
#define L_ 100
#define D_ 1024
#define POS_DIM_ 50
#define GM 51200
#define GN 1024
#define GK 1024
#define LDT 40   // padded LDS row stride (halfwords) for A tiles in gemm_hWn

typedef _Float16 half8 __attribute__((ext_vector_type(8)));
typedef _Float16 half4 __attribute__((ext_vector_type(4)));
typedef float floatx4 __attribute__((ext_vector_type(4)));

// ---------- fast device math ----------
__device__ __forceinline__ float fast_tanh(float x) {
    float e = __expf(2.0f * x);
    return 1.0f - 2.0f * __builtin_amdgcn_rcpf(e + 1.0f);
}
__device__ __forceinline__ float fast_sigmoid(float x) {
    return __builtin_amdgcn_rcpf(1.0f + __expf(-x));
}

// async global->LDS, 16B per lane; lds base must be wave-uniform
__device__ __forceinline__ void gll16(const void* g, void* l) {
    __builtin_amdgcn_global_load_lds(
        (const __attribute__((address_space(1))) void*)g,
        (__attribute__((address_space(3))) void*)l, 16, 0, 0);
}

// ---------- Kernel 1: docs (masked mean) + f16 hi/lo split of docs ----------
__global__ __launch_bounds__(256) void docs_kernel(
    const float* __restrict__ sent, const int* __restrict__ doc_lens,
    _Float16* __restrict__ docs_hi, _Float16* __restrict__ docs_lo)
{
    int b = blockIdx.x;
    int tid = threadIdx.x;
    int len = doc_lens[b];
    float inv = 1.0f / (float)len;
    const float* p = sent + (size_t)b * L_ * D_ + tid * 4;
    float4 acc = {0.f, 0.f, 0.f, 0.f};
    for (int l = 0; l < len; ++l) {
        float4 v = *(const float4*)(p + (size_t)l * D_);
        acc.x += v.x; acc.y += v.y; acc.z += v.z; acc.w += v.w;
    }
    float a[4] = {acc.x * inv, acc.y * inv, acc.z * inv, acc.w * inv};
    half4 h, lo;
    #pragma unroll
    for (int i = 0; i < 4; ++i) {
        _Float16 hi = (_Float16)a[i];
        h[i] = hi;
        lo[i] = (_Float16)(a[i] - (float)hi);
    }
    *(half4*)(docs_hi + (size_t)b * D_ + tid * 4) = h;
    *(half4*)(docs_lo + (size_t)b * D_ + tid * 4) = lo;
}

// ---------- Kernel 2: tiny embedding dots ----------
__global__ void emb_kernel(const float* __restrict__ abs_emb,
                           const float* __restrict__ rel_emb,
                           const float* __restrict__ abs_w,
                           const float* __restrict__ rel_w,
                           float* __restrict__ abs_p, float* __restrict__ rel_vals)
{
    int t = threadIdx.x;
    if (t < L_) {
        float a = 0.f;
        for (int j = 0; j < POS_DIM_; ++j) a += abs_emb[t * POS_DIM_ + j] * abs_w[j];
        abs_p[t] = a;
    }
    if (t < 10) {
        float r = 0.f;
        for (int j = 0; j < POS_DIM_; ++j) r += rel_emb[t * POS_DIM_ + j] * rel_w[j];
        rel_vals[t] = r;
    }
}

// ---------- Kernel 3: elementwise f16 hi/lo split of fc_w and sal_w ----------
__global__ __launch_bounds__(256) void wsplit_kernel(
    const float* __restrict__ fc_w, const float* __restrict__ sal_w,
    _Float16* __restrict__ fcw_hi, _Float16* __restrict__ fcw_lo,
    _Float16* __restrict__ salw_hi, _Float16* __restrict__ salw_lo)
{
    int id = blockIdx.x * 256 + threadIdx.x;
    int base = id * 4;
    const int NN = D_ * D_;
    const float* src; _Float16* dh; _Float16* dl; int off;
    if (base < NN) { src = fc_w; dh = fcw_hi; dl = fcw_lo; off = base; }
    else           { src = sal_w; dh = salw_hi; dl = salw_lo; off = base - NN; }
    float4 v = *(const float4*)(src + off);
    float a[4] = {v.x, v.y, v.z, v.w};
    half4 h, lo;
    #pragma unroll
    for (int i = 0; i < 4; ++i) {
        _Float16 hi = (_Float16)a[i];
        h[i] = hi;
        lo[i] = (_Float16)(a[i] - (float)hi);
    }
    *(half4*)(dh + off) = h;
    *(half4*)(dl + off) = lo;
}

// ---------- Kernel 4: transpose + f16 hi/lo split of nov_w ----------
__global__ __launch_bounds__(256) void convert_b(
    const float* __restrict__ B, _Float16* __restrict__ Bt_hi,
    _Float16* __restrict__ Bt_lo)
{
    __shared__ float ld[32][33];
    int k0 = blockIdx.x * 32, n0 = blockIdx.y * 32;
    int r  = threadIdx.x >> 3;
    int c4 = (threadIdx.x & 7) * 4;
    float4 v = *(const float4*)(B + (size_t)(k0 + r) * D_ + n0 + c4);
    ld[r][c4] = v.x; ld[r][c4 + 1] = v.y; ld[r][c4 + 2] = v.z; ld[r][c4 + 3] = v.w;
    __syncthreads();
    half4 h, l;
    #pragma unroll
    for (int i = 0; i < 4; ++i) {
        float x = ld[c4 + i][r];
        _Float16 hi = (_Float16)x;
        h[i] = hi;
        l[i] = (_Float16)(x - (float)hi);
    }
    *(half4*)(Bt_hi + (size_t)(n0 + r) * D_ + k0 + c4) = h;
    *(half4*)(Bt_lo + (size_t)(n0 + r) * D_ + k0 + c4) = l;
}

// ---------- Kernel 5: MFMA 3-pass f16-split GEMM for small GEMMs ----------
// A (hi/lo) [M,K] f16, B (hi/lo) [N,K] f16; all staging via global_load_lds.
// EPI 1: v = tanh(acc+X[n]) -> write f16 hi/lo pair (Oh, Ol)
// EPI 2: v = acc+X[n]       -> write fp32 O
template<int EPI>
__global__ __launch_bounds__(256, 2) void gemm_ms(
    const _Float16* __restrict__ Ah, const _Float16* __restrict__ Al,
    const _Float16* __restrict__ Bh, const _Float16* __restrict__ Bl,
    const float* __restrict__ X, float* __restrict__ O,
    _Float16* __restrict__ Oh, _Float16* __restrict__ Ol)
{
    __shared__ _Float16 sAh[128 * 32];
    __shared__ _Float16 sAl[128 * 32];
    __shared__ _Float16 sBh[128 * 32];
    __shared__ _Float16 sBl[128 * 32];

    int tid = threadIdx.x;
    int wave = tid >> 6, lane = tid & 63;
    int n0 = blockIdx.x * 128, m0 = blockIdx.y * 128;
    int wm = (wave >> 1) * 64, wn = (wave & 1) * 64;
    int tm = lane & 15, quad = lane >> 4;

    floatx4 acc[4][4];
    #pragma unroll
    for (int i = 0; i < 4; ++i)
        #pragma unroll
        for (int j = 0; j < 4; ++j)
            acc[i][j] = (floatx4){0.f, 0.f, 0.f, 0.f};

    int grow = lane >> 2;          // 0..15
    int gcol = (lane & 3) * 8;     // halfword offset
    const _Float16* pAh = Ah + (size_t)(m0 + wave * 32 + grow) * GK + gcol;
    const _Float16* pAl = Al + (size_t)(m0 + wave * 32 + grow) * GK + gcol;
    const _Float16* pBh = Bh + (size_t)(n0 + wave * 32 + grow) * GK + gcol;
    const _Float16* pBl = Bl + (size_t)(n0 + wave * 32 + grow) * GK + gcol;
    _Float16* lAh = sAh + wave * 32 * 32;
    _Float16* lAl = sAl + wave * 32 * 32;
    _Float16* lBh = sBh + wave * 32 * 32;
    _Float16* lBl = sBl + wave * 32 * 32;

    #pragma unroll 1
    for (int k0 = 0; k0 < GK; k0 += 32) {
        __syncthreads();   // previous iteration's fragment reads complete
        gll16(pAh + k0, lAh);
        gll16(pAh + 16 * GK + k0, lAh + 16 * 32);
        gll16(pAl + k0, lAl);
        gll16(pAl + 16 * GK + k0, lAl + 16 * 32);
        gll16(pBh + k0, lBh);
        gll16(pBh + 16 * GK + k0, lBh + 16 * 32);
        gll16(pBl + k0, lBl);
        gll16(pBl + 16 * GK + k0, lBl + 16 * 32);
        __syncthreads();   // drains vmcnt(0): LDS tile ready

        half8 fah[4], fal[4], fbh[4], fbl[4];
        #pragma unroll
        for (int mt = 0; mt < 4; ++mt) {
            int base = (wm + mt * 16 + tm) * 32 + quad * 8;
            fah[mt] = *(const half8*)(sAh + base);
            fal[mt] = *(const half8*)(sAl + base);
        }
        #pragma unroll
        for (int nt = 0; nt < 4; ++nt) {
            int base = (wn + nt * 16 + tm) * 32 + quad * 8;
            fbh[nt] = *(const half8*)(sBh + base);
            fbl[nt] = *(const half8*)(sBl + base);
        }
        #pragma unroll
        for (int mt = 0; mt < 4; ++mt)
            #pragma unroll
            for (int nt = 0; nt < 4; ++nt) {
                acc[mt][nt] = __builtin_amdgcn_mfma_f32_16x16x32_f16(
                    fah[mt], fbh[nt], acc[mt][nt], 0, 0, 0);
                acc[mt][nt] = __builtin_amdgcn_mfma_f32_16x16x32_f16(
                    fah[mt], fbl[nt], acc[mt][nt], 0, 0, 0);
                acc[mt][nt] = __builtin_amdgcn_mfma_f32_16x16x32_f16(
                    fal[mt], fbh[nt], acc[mt][nt], 0, 0, 0);
            }
    }

    #pragma unroll
    for (int mt = 0; mt < 4; ++mt) {
        #pragma unroll
        for (int nt = 0; nt < 4; ++nt) {
            int col = n0 + wn + nt * 16 + tm;
            int rowb = m0 + wm + mt * 16 + quad * 4;
            float xv = X[col];
            #pragma unroll
            for (int r = 0; r < 4; ++r) {
                float v = acc[mt][nt][r];
                if (EPI == 1) {
                    v = tanhf(v + xv);
                    _Float16 hi = (_Float16)v;
                    Oh[(size_t)(rowb + r) * GN + col] = hi;
                    Ol[(size_t)(rowb + r) * GN + col] = (_Float16)(v - (float)hi);
                } else {
                    O[(size_t)(rowb + r) * GN + col] = v + xv;
                }
            }
        }
    }
}

// ---------- Kernel 6: MFMA f16-split GEMM: hWn = sent @ nov_w ----------
// A fp32 split on the fly (VALU); B (pre-split) staged via global_load_lds.
// XCD swizzle: d = g*64 + n*8 + i, m = g*8 + i  (8 n-blocks of a slab share d%8)
__global__ __launch_bounds__(256, 2) void gemm_hWn(
    const float* __restrict__ A, const _Float16* __restrict__ Bt_hi,
    const _Float16* __restrict__ Bt_lo, float* __restrict__ C)
{
    __shared__ _Float16 As_hi[128 * LDT];
    __shared__ _Float16 As_lo[128 * LDT];
    __shared__ _Float16 Bs_hi[128 * 32];
    __shared__ _Float16 Bs_lo[128 * 32];

    int tid  = threadIdx.x;
    int wave = tid >> 6, lane = tid & 63;
    int d = blockIdx.x;
    int islab = d & 7, nblk = (d >> 3) & 7, g = d >> 6;
    int m0 = (g * 8 + islab) * 128;
    int n0 = nblk * 128;
    int wm = (wave >> 1) * 64, wn = (wave & 1) * 64;
    int tm   = lane & 15;
    int quad = lane >> 4;

    floatx4 acc[4][4];
    #pragma unroll
    for (int i = 0; i < 4; ++i)
        #pragma unroll
        for (int j = 0; j < 4; ++j)
            acc[i][j] = (floatx4){0.f, 0.f, 0.f, 0.f};

    // A staging: thread covers (row, 16-elem k-half)
    int sr = tid >> 1;
    int sh = tid & 1;
    const float* Ap = A + (size_t)(m0 + sr) * GK + sh * 16;
    int sbase = sr * LDT + sh * 16;

    // B staging via gll: wave covers rows [wave*32, wave*32+32)
    int grow = lane >> 2;
    int gcol = (lane & 3) * 8;
    const _Float16* pBh = Bt_hi + (size_t)(n0 + wave * 32 + grow) * GK + gcol;
    const _Float16* pBl = Bt_lo + (size_t)(n0 + wave * 32 + grow) * GK + gcol;
    _Float16* lBh = Bs_hi + wave * 32 * 32;
    _Float16* lBl = Bs_lo + wave * 32 * 32;

    #pragma unroll 1
    for (int k0 = 0; k0 < GK; k0 += 32) {
        float4 a0 = *(const float4*)(Ap + k0);
        float4 a1 = *(const float4*)(Ap + k0 + 4);
        float4 a2 = *(const float4*)(Ap + k0 + 8);
        float4 a3 = *(const float4*)(Ap + k0 + 12);

        half8 ah0, ah1, al0, al1;
        float af[16] = {a0.x, a0.y, a0.z, a0.w, a1.x, a1.y, a1.z, a1.w,
                        a2.x, a2.y, a2.z, a2.w, a3.x, a3.y, a3.z, a3.w};
        #pragma unroll
        for (int i = 0; i < 8; ++i) {
            _Float16 h = (_Float16)af[i];
            ah0[i] = h;
            al0[i] = (_Float16)(af[i] - (float)h);
        }
        #pragma unroll
        for (int i = 0; i < 8; ++i) {
            _Float16 h = (_Float16)af[8 + i];
            ah1[i] = h;
            al1[i] = (_Float16)(af[8 + i] - (float)h);
        }

        __syncthreads();   // previous iteration's fragment reads complete
        // B DMA into LDS
        gll16(pBh + k0, lBh);
        gll16(pBh + 16 * GK + k0, lBh + 16 * 32);
        gll16(pBl + k0, lBl);
        gll16(pBl + 16 * GK + k0, lBl + 16 * 32);
        // A stores
        *(half8*)(As_hi + sbase)     = ah0;
        *(half8*)(As_hi + sbase + 8) = ah1;
        *(half8*)(As_lo + sbase)     = al0;
        *(half8*)(As_lo + sbase + 8) = al1;
        __syncthreads();   // drains vmcnt (gll) + lgkm (stores)

        half8 fa_hi[4], fa_lo[4], fb_hi[4], fb_lo[4];
        #pragma unroll
        for (int mt = 0; mt < 4; ++mt) {
            int row = (wm + mt * 16 + tm) * LDT + quad * 8;
            fa_hi[mt] = *(const half8*)(As_hi + row);
            fa_lo[mt] = *(const half8*)(As_lo + row);
        }
        #pragma unroll
        for (int nt = 0; nt < 4; ++nt) {
            int row = (wn + nt * 16 + tm) * 32 + quad * 8;
            fb_hi[nt] = *(const half8*)(Bs_hi + row);
            fb_lo[nt] = *(const half8*)(Bs_lo + row);
        }
        #pragma unroll
        for (int mt = 0; mt < 4; ++mt)
            #pragma unroll
            for (int nt = 0; nt < 4; ++nt) {
                acc[mt][nt] = __builtin_amdgcn_mfma_f32_16x16x32_f16(
                    fa_hi[mt], fb_hi[nt], acc[mt][nt], 0, 0, 0);
                acc[mt][nt] = __builtin_amdgcn_mfma_f32_16x16x32_f16(
                    fa_hi[mt], fb_lo[nt], acc[mt][nt], 0, 0, 0);
                acc[mt][nt] = __builtin_amdgcn_mfma_f32_16x16x32_f16(
                    fa_lo[mt], fb_hi[nt], acc[mt][nt], 0, 0, 0);
            }
    }

    #pragma unroll
    for (int mt = 0; mt < 4; ++mt) {
        #pragma unroll
        for (int nt = 0; nt < 4; ++nt) {
            int col = n0 + wn + nt * 16 + tm;
            int rowb = m0 + wm + mt * 16 + quad * 4;
            #pragma unroll
            for (int r = 0; r < 4; ++r)
                C[(size_t)(rowb + r) * GN + col] = acc[mt][nt][r];
        }
    }
}

// ---------- Kernel 7: scan — one wave per batch, all-register ----------
__global__ __launch_bounds__(64) void scan_kernel(
    const float* __restrict__ sent, const float* __restrict__ hWn,
    const float* __restrict__ u, const float* __restrict__ abs_p,
    const float* __restrict__ rel_vals, const float* __restrict__ bias,
    const int* __restrict__ doc_lens, float* __restrict__ out)
{
    int b = blockIdx.x;
    int lane = threadIdx.x;
    int len = doc_lens[b];
    float lenf = (float)len;

    for (int l = len + lane; l < L_; l += 64) out[b * L_ + l] = 0.f;

    // lane owns cols {lane*4 + j*256 : j=0..3, +0..3}
    const float* ub = u + (size_t)b * D_ + lane * 4;
    float ur[16], s[16];
    #pragma unroll
    for (int j = 0; j < 4; ++j) {
        *(float4*)(ur + 4 * j) = *(const float4*)(ub + 256 * j);
    }
    #pragma unroll
    for (int i = 0; i < 16; ++i) s[i] = 0.f;

    const float* sb = sent + (size_t)b * L_ * D_ + lane * 4;
    const float* wb = hWn  + (size_t)b * L_ * D_ + lane * 4;
    float biasv = bias[0];

    float hA[16], wA[16], hB[16], wB[16];

    auto loadrow = [&](int row, float* hh, float* ww) {
        const float* ph = sb + (size_t)row * D_;
        const float* pw = wb + (size_t)row * D_;
        #pragma unroll
        for (int j = 0; j < 4; ++j) {
            *(float4*)(hh + 4 * j) = *(const float4*)(ph + 256 * j);
            *(float4*)(ww + 4 * j) = *(const float4*)(pw + 256 * j);
        }
    };

    auto step = [&](int t, const float* hh, const float* ww) {
        float r1 = 0.f, r2 = 0.f;
        #pragma unroll
        for (int i = 0; i < 16; ++i) {
            r1 = fmaf(ww[i], fast_tanh(s[i]), r1);
            r2 = fmaf(hh[i], ur[i], r2);
        }
        #pragma unroll
        for (int off = 32; off; off >>= 1) {
            r1 += __shfl_xor(r1, off);
            r2 += __shfl_xor(r2, off);
        }
        int ridx = (int)rintf((float)(t + 1) * 9.0f / lenf);
        ridx = min(max(ridx, 0), 9);
        float pre = r2 + abs_p[t] + rel_vals[ridx] + biasv - r1;
        float prob = fast_sigmoid(pre);
        if (lane == 0) out[b * L_ + t] = prob;
        #pragma unroll
        for (int i = 0; i < 16; ++i) s[i] = fmaf(prob, hh[i], s[i]);
    };

    loadrow(0, hA, wA);
    int t = 0;
    while (true) {
        int tn = min(t + 1, len - 1);
        loadrow(tn, hB, wB);
        step(t, hA, wA);
        ++t; if (t >= len) break;
        tn = min(t + 1, len - 1);
        loadrow(tn, hA, wA);
        step(t, hB, wB);
        ++t; if (t >= len) break;
    }
}

// ---------- launch ----------
extern "C" void kernel_launch(void* const* d_in, const int* in_sizes, int n_in,
                              void* d_out, int out_size, void* d_ws, size_t ws_size,
                              hipStream_t stream)
{
    const float* sent      = (const float*)d_in[0];
    const float* fc_w      = (const float*)d_in[1];
    const float* fc_b      = (const float*)d_in[2];
    const float* content_w = (const float*)d_in[3];
    const float* sal_w     = (const float*)d_in[4];
    const float* nov_w     = (const float*)d_in[5];
    const float* abs_emb   = (const float*)d_in[6];
    const float* rel_emb   = (const float*)d_in[7];
    const float* abs_w     = (const float*)d_in[8];
    const float* rel_w     = (const float*)d_in[9];
    const float* bias      = (const float*)d_in[10];
    const int*   doc_lens  = (const int*)d_in[11];
    float* out = (float*)d_out;

    char* ws = (char*)d_ws;
    const size_t MB = 1024 * 1024;
    _Float16* docs_hi = (_Float16*)(ws);             // 1 MiB
    _Float16* docs_lo = (_Float16*)(ws + 1 * MB);    // 1 MiB
    _Float16* dv_hi   = (_Float16*)(ws + 2 * MB);    // 1 MiB
    _Float16* dv_lo   = (_Float16*)(ws + 3 * MB);    // 1 MiB
    float*    u       = (float*)(ws + 4 * MB);       // 2 MiB
    float*    abs_p   = (float*)(ws + 6 * MB);
    float*    rel_vals= (float*)(ws + 6 * MB + 512);
    _Float16* fcw_hi  = (_Float16*)(ws + 7 * MB);    // 2 MiB
    _Float16* fcw_lo  = (_Float16*)(ws + 9 * MB);    // 2 MiB
    _Float16* salw_hi = (_Float16*)(ws + 11 * MB);   // 2 MiB
    _Float16* salw_lo = (_Float16*)(ws + 13 * MB);   // 2 MiB
    _Float16* Bt_hi   = (_Float16*)(ws + 15 * MB);   // 2 MiB
    _Float16* Bt_lo   = (_Float16*)(ws + 17 * MB);   // 2 MiB
    float*    hWn     = (float*)(ws + 20 * MB);      // 200 MiB

    // 1) docs masked mean + split
    docs_kernel<<<dim3(B_), 256, 0, stream>>>(sent, doc_lens, docs_hi, docs_lo);

    // 2) embedding dots
    emb_kernel<<<dim3(1), 128, 0, stream>>>(abs_emb, rel_emb, abs_w, rel_w, abs_p, rel_vals);

    // 3) split fc_w / sal_w (already [N,K] layout)
    wsplit_kernel<<<dim3(2 * D_ * D_ / (256 * 4)), 256, 0, stream>>>(
        fc_w, sal_w, fcw_hi, fcw_lo, salw_hi, salw_lo);

    // 4) transpose + split nov_w
    convert_b<<<dim3(32, 32), 256, 0, stream>>>(nov_w, Bt_hi, Bt_lo);

    // 5) hWn = sent @ nov_w  (XCD-swizzled 1D grid: 50 groups * 64 blocks)
    gemm_hWn<<<dim3(3200), 256, 0, stream>>>(sent, Bt_hi, Bt_lo, hWn);

    // 6) doc_vec = tanh(docs @ fc_w^T + fc_b) -> f16 pair
    gemm_ms<1><<<dim3(D_ / 128, B_ / 128), 256, 0, stream>>>(
        docs_hi, docs_lo, fcw_hi, fcw_lo, fc_b, nullptr, dv_hi, dv_lo);

    // 7) u = doc_vec @ sal_w^T + content_w -> fp32
    gemm_ms<2><<<dim3(D_ / 128, B_ / 128), 256, 0, stream>>>(
        dv_hi, dv_lo, salw_hi, salw_lo, content_w, u, nullptr, nullptr);

    // 8) scan: one wave per batch
    scan_kernel<<<dim3(B_), 64, 0, stream>>>(
        sent, hWn, u, abs_p, rel_vals, bias, doc_lens, out);
}